// Round 1
// baseline (100.880 us; speedup 1.0000x reference)
//
#include <hip/hip_runtime.h>

constexpr int H = 192, W = 192, D = 192;
constexpr int N = H * W * D;

// Ip[yy, xx, zz]: zero-padded (194^3) view of I (192^3). Interior is [1, 192].
__device__ __forceinline__ float fetchI(const float* __restrict__ I, int yy, int xx, int zz) {
    bool inb = (unsigned)(yy - 1) < (unsigned)H
            && (unsigned)(xx - 1) < (unsigned)W
            && (unsigned)(zz - 1) < (unsigned)D;
    if (!inb) return 0.0f;
    return I[((yy - 1) * W + (xx - 1)) * D + (zz - 1)];
}

__global__ __launch_bounds__(256) void st_trilinear(
    const float* __restrict__ I,
    const float* __restrict__ dxt,
    const float* __restrict__ dyt,
    const float* __restrict__ dzt,
    float* __restrict__ out)
{
    int t = blockIdx.x * blockDim.x + threadIdx.x;
    if (t >= N / 4) return;
    int base = t * 4;
    int d0 = base % D;        // D=192 divisible by 4 -> 4 elems share (h,w)
    int hw = base / D;
    int w = hw % W;
    int h = hw / W;

    float4 vx = reinterpret_cast<const float4*>(dxt)[t];
    float4 vy = reinterpret_cast<const float4*>(dyt)[t];
    float4 vz = reinterpret_cast<const float4*>(dzt)[t];

    float rx[4] = {vx.x, vx.y, vx.z, vx.w};
    float ry[4] = {vy.x, vy.y, vy.z, vy.w};
    float rz[4] = {vz.x, vz.y, vz.z, vz.w};
    float ro[4];

    #pragma unroll
    for (int j = 0; j < 4; ++j) {
        float x = rx[j] + (float)(w + 1);
        float y = ry[j] + (float)(h + 1);
        float z = rz[j] + (float)(d0 + j + 1);

        int fx = (int)floorf(x);
        int fy = (int)floorf(y);
        int fz = (int)floorf(z);

        int x0 = min(max(fx, 0), W + 1);
        int x1 = min(max(fx + 1, 0), W + 1);
        int y0 = min(max(fy, 0), H + 1);
        int y1 = min(max(fy + 1, 0), H + 1);
        int z0 = min(max(fz, 0), D + 1);
        int z1 = min(max(fz + 1, 0), D + 1);

        // NOTE: dx/dy/dz computed from the *clipped* +1 neighbor, per reference.
        float dx = (float)x1 - x;
        float dy = (float)y1 - y;
        float dz = (float)z1 - z;
        float omdx = 1.0f - dx, omdy = 1.0f - dy, omdz = 1.0f - dz;

        float Ia = fetchI(I, y0, x0, z0);
        float Ib = fetchI(I, y1, x0, z0);
        float Ic = fetchI(I, y0, x1, z0);
        float Id = fetchI(I, y1, x1, z0);
        float Ie = fetchI(I, y0, x0, z1);
        float If = fetchI(I, y1, x0, z1);
        float Ig = fetchI(I, y0, x1, z1);
        float Ih = fetchI(I, y1, x1, z1);

        ro[j] = dz   * (dx * (dy * Ia + omdy * Ib) + omdx * (dy * Ic + omdy * Id))
              + omdz * (dx * (dy * Ie + omdy * If) + omdx * (dy * Ig + omdy * Ih));
    }

    reinterpret_cast<float4*>(out)[t] = make_float4(ro[0], ro[1], ro[2], ro[3]);
}

extern "C" void kernel_launch(void* const* d_in, const int* in_sizes, int n_in,
                              void* d_out, int out_size, void* d_ws, size_t ws_size,
                              hipStream_t stream) {
    const float* I   = (const float*)d_in[0];
    const float* dxt = (const float*)d_in[1];
    const float* dyt = (const float*)d_in[2];
    const float* dzt = (const float*)d_in[3];
    float* out = (float*)d_out;

    int total = N / 4;               // one thread per 4 consecutive d-voxels
    int threads = 256;
    int blocks = (total + threads - 1) / threads;
    hipLaunchKernelGGL(st_trilinear, dim3(blocks), dim3(threads), 0, stream,
                       I, dxt, dyt, dzt, out);
}

// Round 2
// 66.136 us; speedup vs baseline: 1.5253x; 1.5253x over previous
//
#include <hip/hip_runtime.h>

constexpr int H = 192, W = 192, D = 192;
constexpr int N = H * W * D;

// 8-byte pair with only 4-byte alignment guarantee (z offset has arbitrary parity).
struct __attribute__((aligned(4))) f2u { float x, y; };

__global__ __launch_bounds__(256) void st_trilinear(
    const float* __restrict__ I,
    const float* __restrict__ dxt,
    const float* __restrict__ dyt,
    const float* __restrict__ dzt,
    float* __restrict__ out)
{
    int t = blockIdx.x * blockDim.x + threadIdx.x;   // N/4 = 1769472, exact multiple of 256
    int base = t * 4;
    int d0 = base % D;            // 4 consecutive z share (h,w)
    int hw = base / D;
    int w = hw % W;
    int h = hw / W;

    float4 vx = reinterpret_cast<const float4*>(dxt)[t];
    float4 vy = reinterpret_cast<const float4*>(dyt)[t];
    float4 vz = reinterpret_cast<const float4*>(dzt)[t];

    float rx[4] = {vx.x, vx.y, vx.z, vx.w};
    float ry[4] = {vy.x, vy.y, vy.z, vy.w};
    float rz[4] = {vz.x, vz.y, vz.z, vz.w};

    // Phase A: per-voxel weights (with OOB folded in) + 4 row-base offsets + z select flags
    float ax0[4], ax1[4], ay0[4], ay1[4], az0[4], az1[4];
    int   off00[4], off01[4], off10[4], off11[4];   // (y0,x0) (y0,x1) (y1,x0) (y1,x1) + zc
    bool  zlo[4], zhi[4];

    #pragma unroll
    for (int j = 0; j < 4; ++j) {
        float x = rx[j] + (float)(w + 1);
        float y = ry[j] + (float)(h + 1);
        float z = rz[j] + (float)(d0 + j + 1);

        int fx = (int)floorf(x);
        int fy = (int)floorf(y);
        int fz = (int)floorf(z);

        // padded-coord clip [0, 193]
        int x0 = min(max(fx, 0), W + 1), x1 = min(max(fx + 1, 0), W + 1);
        int y0 = min(max(fy, 0), H + 1), y1 = min(max(fy + 1, 0), H + 1);
        int z0 = min(max(fz, 0), D + 1), z1 = min(max(fz + 1, 0), D + 1);

        float dx = (float)x1 - x;
        float dy = (float)y1 - y;
        float dz = (float)z1 - z;

        // unpadded indices
        int xi0 = x0 - 1, xi1 = x1 - 1;
        int yi0 = y0 - 1, yi1 = y1 - 1;
        int zi  = z0 - 1, zj  = z1 - 1;

        // fold OOB-zero into weights
        ax0[j] = ((unsigned)xi0 < (unsigned)W) ? dx          : 0.0f;
        ax1[j] = ((unsigned)xi1 < (unsigned)W) ? 1.0f - dx   : 0.0f;
        ay0[j] = ((unsigned)yi0 < (unsigned)H) ? dy          : 0.0f;
        ay1[j] = ((unsigned)yi1 < (unsigned)H) ? 1.0f - dy   : 0.0f;
        az0[j] = ((unsigned)zi  < (unsigned)D) ? dz          : 0.0f;
        az1[j] = ((unsigned)zj  < (unsigned)D) ? 1.0f - dz   : 0.0f;

        // clamped addresses (loads always legal; bogus values killed by zero weights)
        int xc0 = min(max(xi0, 0), W - 1), xc1 = min(max(xi1, 0), W - 1);
        int yc0 = min(max(yi0, 0), H - 1), yc1 = min(max(yi1, 0), H - 1);
        int zc  = min(max(zi, 0), D - 2);          // pair load [zc, zc+1] always in-bounds

        zlo[j] = (zi <= D - 2);   // z0 value at pair.x, else pair.y (zi == 191 case)
        zhi[j] = (zi >= 0);       // z1 value at pair.y, else pair.x (zi == -1 case)

        off00[j] = (yc0 * W + xc0) * D + zc;
        off01[j] = (yc0 * W + xc1) * D + zc;
        off10[j] = (yc1 * W + xc0) * D + zc;
        off11[j] = (yc1 * W + xc1) * D + zc;
    }

    // Phase B: issue all 16 pair-gathers unconditionally
    f2u p00[4], p01[4], p10[4], p11[4];
    #pragma unroll
    for (int j = 0; j < 4; ++j) {
        p00[j] = *reinterpret_cast<const f2u*>(I + off00[j]);
        p01[j] = *reinterpret_cast<const f2u*>(I + off01[j]);
        p10[j] = *reinterpret_cast<const f2u*>(I + off10[j]);
        p11[j] = *reinterpret_cast<const f2u*>(I + off11[j]);
    }

    // Phase C: weighted sum
    float ro[4];
    #pragma unroll
    for (int j = 0; j < 4; ++j) {
        float v000 = zlo[j] ? p00[j].x : p00[j].y;   // (y0,x0,z0)
        float v001 = zhi[j] ? p00[j].y : p00[j].x;   // (y0,x0,z1)
        float v010 = zlo[j] ? p01[j].x : p01[j].y;   // (y0,x1,z0)
        float v011 = zhi[j] ? p01[j].y : p01[j].x;
        float v100 = zlo[j] ? p10[j].x : p10[j].y;   // (y1,x0,z0)
        float v101 = zhi[j] ? p10[j].y : p10[j].x;
        float v110 = zlo[j] ? p11[j].x : p11[j].y;   // (y1,x1,z0)
        float v111 = zhi[j] ? p11[j].y : p11[j].x;

        // out = sum over (x-side, y-side): ax*ay*(az0*v_z0 + az1*v_z1)
        float s00 = az0[j] * v000 + az1[j] * v001;   // x0,y0
        float s01 = az0[j] * v010 + az1[j] * v011;   // x1,y0
        float s10 = az0[j] * v100 + az1[j] * v101;   // x0,y1
        float s11 = az0[j] * v110 + az1[j] * v111;   // x1,y1

        ro[j] = ay0[j] * (ax0[j] * s00 + ax1[j] * s01)
              + ay1[j] * (ax0[j] * s10 + ax1[j] * s11);
    }

    reinterpret_cast<float4*>(out)[t] = make_float4(ro[0], ro[1], ro[2], ro[3]);
}

extern "C" void kernel_launch(void* const* d_in, const int* in_sizes, int n_in,
                              void* d_out, int out_size, void* d_ws, size_t ws_size,
                              hipStream_t stream) {
    const float* I   = (const float*)d_in[0];
    const float* dxt = (const float*)d_in[1];
    const float* dyt = (const float*)d_in[2];
    const float* dzt = (const float*)d_in[3];
    float* out = (float*)d_out;

    int total = N / 4;
    int threads = 256;
    int blocks = total / threads;    // exact
    hipLaunchKernelGGL(st_trilinear, dim3(blocks), dim3(threads), 0, stream,
                       I, dxt, dyt, dzt, out);
}